// Round 1
// baseline (181.558 us; speedup 1.0000x reference)
//
#include <hip/hip_runtime.h>

// Problem constants (from reference): F=32 fields, B=8192 batch, D=64 embed.
// out[b, r*D + c] = s[b,r] * s[b,c], where s[b,d] = sum_f in[f,b,0,d].
// Memory-bound: 64 MiB read + 128 MiB write -> ~32 us floor at 6.3 TB/s.

#define NF 32
#define NB 8192
#define ND 64

__global__ __launch_bounds__(256) void opnn_outer_kernel(
    const float* __restrict__ in, float* __restrict__ out) {
    const int tid = threadIdx.x;
    const int b   = blockIdx.x;
    const int g    = tid >> 4;   // field-group 0..15 (2 fields each)
    const int dvec = tid & 15;   // float4 index within D (16 float4 = 64 floats)

    // ---- Stage 1: s[d] = sum over 32 fields, vectorized float4 ----
    // float4 index of element (f, b, d0=dvec*4): (f*NB + b)*16 + dvec
    const float4* in4 = (const float4*)in;
    size_t i0 = ((size_t)(2 * g)     * NB + b) * (ND / 4) + dvec;
    size_t i1 = ((size_t)(2 * g + 1) * NB + b) * (ND / 4) + dvec;
    float4 a0 = in4[i0];
    float4 a1 = in4[i1];
    float4 acc = make_float4(a0.x + a1.x, a0.y + a1.y, a0.z + a1.z, a0.w + a1.w);

    __shared__ float4 part[16][16];  // [group][dvec]
    __shared__ float4 s4[16];        // s[64] as 16 float4, 16B-aligned
    part[g][dvec] = acc;
    __syncthreads();

    if (tid < 16) {
        float4 sum = part[0][tid];
        #pragma unroll
        for (int gg = 1; gg < 16; ++gg) {
            float4 p = part[gg][tid];
            sum.x += p.x; sum.y += p.y; sum.z += p.z; sum.w += p.w;
        }
        s4[tid] = sum;
    }
    __syncthreads();

    // ---- Stage 2: outer product, 1024 float4 per sample, coalesced ----
    const float* s = (const float*)s4;
    float4* out4 = (float4*)(out + (size_t)b * (ND * ND));
    #pragma unroll
    for (int j = 0; j < 4; ++j) {
        int idx4 = j * 256 + tid;    // 0..1023
        int r  = idx4 >> 4;          // row 0..63 (16 float4 per row)
        int cv = idx4 & 15;          // float4 col index
        float  sr = s[r];            // LDS broadcast within 16-lane groups
        float4 sc = s4[cv];          // LDS broadcast
        out4[idx4] = make_float4(sr * sc.x, sr * sc.y, sr * sc.z, sr * sc.w);
    }
}

extern "C" void kernel_launch(void* const* d_in, const int* in_sizes, int n_in,
                              void* d_out, int out_size, void* d_ws, size_t ws_size,
                              hipStream_t stream) {
    const float* in = (const float*)d_in[0];
    float* out = (float*)d_out;
    opnn_outer_kernel<<<NB, 256, 0, stream>>>(in, out);
}

// Round 3
// 174.096 us; speedup vs baseline: 1.0429x; 1.0429x over previous
//
#include <hip/hip_runtime.h>

// F=32 fields, B=8192 batch, D=64.
// out[b, r*64+c] = s[b,r]*s[b,c], s[b,d] = sum_f in[f,b,0,d].
// Memory-bound: 64 MiB read + 128 MiB write -> ~32 us floor at 6.3 TB/s.
//
// Decomposition: 1 wave owns 4 consecutive samples.
//   lane = lb*16 + dv,  lb = sample-in-wave (0..3), dv = float4 chunk of D (0..15)
//   Stage 1: acc[lane] = sum_f in4[(f*B + b)*16 + dv] -- for fixed f a wave's 64
//            lanes touch a contiguous 1 KiB segment (perfect coalescing), and the
//            field-sum lives entirely in one lane: NO cross-lane reduction.
//   Stage 2: out4[idx4], idx4 = it*64+lane -> r = it*4+lb, c4 = dv. sc is
//            lane-invariant across `it` (hoisted); s[r] is one scalar LDS read.
//            Stores are contiguous 1 KiB per wave-instruction, nontemporal.

#define NF 32
#define NB 8192
#define ND 64

typedef float f4 __attribute__((ext_vector_type(4)));  // native vec: OK for nontemporal builtins

__global__ __launch_bounds__(256) void opnn_outer_kernel(
    const float* __restrict__ in, float* __restrict__ out) {
    const int tid  = threadIdx.x;
    const int w    = tid >> 6;        // wave in block: 0..3
    const int lane = tid & 63;
    const int lb   = lane >> 4;       // sample within wave: 0..3
    const int dv   = lane & 15;       // float4 index within D
    const int s_local = w * 4 + lb;   // sample within block: 0..15
    const int b = blockIdx.x * 16 + s_local;

    // ---- Stage 1: per-lane field sum (no reduction needed) ----
    const f4* __restrict__ in4 = (const f4*)in;
    const size_t base = (size_t)b * (ND / 4) + dv;
    f4 acc = (f4)0.f;
    #pragma unroll
    for (int f = 0; f < NF; ++f) {
        f4 v = __builtin_nontemporal_load(&in4[base + (size_t)f * NB * (ND / 4)]);
        acc += v;
    }

    __shared__ f4 sh[16][16];         // [sample-in-block][dv]
    sh[s_local][dv] = acc;
    __syncthreads();

    // ---- Stage 2: outer product, 1 KiB contiguous per store instruction ----
    const float* shf = (const float*)sh;
    #pragma unroll
    for (int ss = 0; ss < 4; ++ss) {
        const int sidx = w * 4 + ss;                       // sample within block
        const f4 sc = sh[sidx][dv];                        // column vec, hoisted
        f4* __restrict__ outp =
            (f4*)(out + ((size_t)blockIdx.x * 16 + sidx) * (ND * ND));
        #pragma unroll
        for (int it = 0; it < 16; ++it) {
            const int r = it * 4 + lb;                     // row 0..63
            const float sr = shf[sidx * 64 + r];           // 4 addrs, 16x broadcast
            f4 v = sr * sc;
            __builtin_nontemporal_store(v, &outp[it * 64 + lane]);
        }
    }
}

extern "C" void kernel_launch(void* const* d_in, const int* in_sizes, int n_in,
                              void* d_out, int out_size, void* d_ws, size_t ws_size,
                              hipStream_t stream) {
    const float* in = (const float*)d_in[0];
    float* out = (float*)d_out;
    opnn_outer_kernel<<<NB / 16, 256, 0, stream>>>(in, out);
}